// Round 1
// 459.534 us; speedup vs baseline: 1.0721x; 1.0721x over previous
//
#include <hip/hip_runtime.h>
#include <hip/hip_bf16.h>

#define NEG_SLOPE 0.2f

typedef __attribute__((ext_vector_type(8))) short short8;
typedef __attribute__((ext_vector_type(4))) float f32x4;

__device__ __forceinline__ float lrelu(float x) { return x >= 0.f ? x : NEG_SLOPE * x; }

// pack two fp32 -> bf16x2 (RNE), low = a, high = b
__device__ __forceinline__ unsigned pack_bf2(float a, float b) {
    unsigned ua = __float_as_uint(a), ub = __float_as_uint(b);
    ua = (ua + 0x7fffu + ((ua >> 16) & 1u)) >> 16;
    ub = (ub + 0x7fffu + ((ub >> 16) & 1u)) & 0xffff0000u;
    return ua | ub;
}
__device__ __forceinline__ float2 unpack_bf2(unsigned u) {
    return make_float2(__uint_as_float(u << 16), __uint_as_float(u & 0xffff0000u));
}
__device__ __forceinline__ unsigned short bf16_of(float a) {
    unsigned ua = __float_as_uint(a);
    return (unsigned short)((ua + 0x7fffu + ((ua >> 16) & 1u)) >> 16);
}

// ---------------- CSR build (round-6: deterministic XCD bucketing, single-read passes) ----------------
// Pass 1: per-block histogram of 8 XCD partitions.
__global__ __launch_bounds__(256) void bcount_kernel(const int* __restrict__ dst,
                                                     int* __restrict__ blk_cnt,
                                                     int etot, int psz, int chunk) {
    __shared__ int cnt[8];
    if (threadIdx.x < 8) cnt[threadIdx.x] = 0;
    __syncthreads();
    int e0 = blockIdx.x * chunk, e1 = min(etot, e0 + chunk);
    for (int e = e0 + (int)threadIdx.x; e < e1; e += 256) {
        int p = min(dst[e] / psz, 7);
        atomicAdd(&cnt[p], 1);
    }
    __syncthreads();
    if (threadIdx.x < 8) blk_cnt[blockIdx.x * 8 + threadIdx.x] = cnt[threadIdx.x];
}

// Pass 2: scan 1024 block-counts per bucket + cross-bucket bases. One block, 1024 threads.
__global__ __launch_bounds__(1024) void bscan_kernel(const int* __restrict__ blk_cnt,
                                                     int* __restrict__ blk_base,
                                                     int* __restrict__ bstart) {
    __shared__ int wsum[16];
    __shared__ int coltot[8];
    __shared__ int colbase[9];
    int t = threadIdx.x;
    int lane = t & 63, wid = t >> 6;
    int v[8], incl[8];
#pragma unroll
    for (int p = 0; p < 8; ++p) v[p] = blk_cnt[t * 8 + p];
#pragma unroll
    for (int p = 0; p < 8; ++p) {
        int x = v[p];
#pragma unroll
        for (int off = 1; off < 64; off <<= 1) {
            int y = __shfl_up(x, off);
            if (lane >= off) x += y;
        }
        if (lane == 63) wsum[wid] = x;
        __syncthreads();
        if (wid == 0) {
            int s = (lane < 16) ? wsum[lane] : 0;
#pragma unroll
            for (int off = 1; off < 16; off <<= 1) {
                int y = __shfl_up(s, off);
                if (lane >= off) s += y;
            }
            if (lane < 16) wsum[lane] = s;
        }
        __syncthreads();
        int base = (wid > 0) ? wsum[wid - 1] : 0;
        incl[p] = base + x;
        if (t == 1023) coltot[p] = incl[p];
        __syncthreads();
    }
    if (t == 0) {
        int acc = 0;
        for (int p = 0; p < 8; ++p) {
            colbase[p] = acc;
            bstart[p] = acc;
            acc += coltot[p];
        }
        colbase[8] = acc;
        bstart[8] = acc;
    }
    __syncthreads();
#pragma unroll
    for (int p = 0; p < 8; ++p) blk_base[t * 8 + p] = colbase[p] + incl[p] - v[p];
}

// Pass 3: scatter edges into per-partition contiguous lists (deterministic bases, LDS ranks).
__global__ __launch_bounds__(256) void bscatter_kernel(const int* __restrict__ src,
                                                       const int* __restrict__ dst,
                                                       const int* __restrict__ blk_base,
                                                       int* __restrict__ src_b,
                                                       int* __restrict__ dst_b,
                                                       int etot, int psz, int chunk) {
    __shared__ int base[8];
    __shared__ int lcnt[8];
    if (threadIdx.x < 8) {
        base[threadIdx.x] = blk_base[blockIdx.x * 8 + threadIdx.x];
        lcnt[threadIdx.x] = 0;
    }
    __syncthreads();
    int e0 = blockIdx.x * chunk, e1 = min(etot, e0 + chunk);
    for (int e = e0 + (int)threadIdx.x; e < e1; e += 256) {
        int d = dst[e], s = src[e];
        int p = min(d / psz, 7);
        int loc = atomicAdd(&lcnt[p], 1);
        int pos = base[p] + loc;
        dst_b[pos] = d;
        src_b[pos] = s;
    }
}

// Pass 4: degree histogram over bucketed list (XCD-local atomics), emit packed (dst | rank<<17).
__global__ __launch_bounds__(256) void histB_kernel(const int* __restrict__ dst_b,
                                                    const int* __restrict__ bstart,
                                                    int* __restrict__ counts,
                                                    int* __restrict__ pk) {
    int part = blockIdx.x & 7, stripe = blockIdx.x >> 3;
    int nstripes = gridDim.x >> 3;
    int b0 = bstart[part], b1 = bstart[part + 1];
    int per = (b1 - b0 + nstripes - 1) / nstripes;
    int e0 = b0 + stripe * per, e1 = min(b1, e0 + per);
    for (int e = e0 + (int)threadIdx.x; e < e1; e += 256) {
        int d = dst_b[e];
        int r = atomicAdd(&counts[d], 1);
        pk[e] = d | (r << 17);
    }
}

__global__ __launch_bounds__(256) void scanA_kernel(const int* __restrict__ counts,
                                                    int* __restrict__ bsums, int n) {
    __shared__ int sm[256];
    int i = blockIdx.x * 256 + threadIdx.x;
    sm[threadIdx.x] = (i < n) ? counts[i] : 0;
    __syncthreads();
    for (int off = 128; off > 0; off >>= 1) {
        if (threadIdx.x < off) sm[threadIdx.x] += sm[threadIdx.x + off];
        __syncthreads();
    }
    if (threadIdx.x == 0) bsums[blockIdx.x] = sm[0];
}

__global__ __launch_bounds__(1024) void scanB_kernel(int* __restrict__ bsums, int nb) {
    __shared__ int sm[1024];
    int t = threadIdx.x;
    int v = (t < nb) ? bsums[t] : 0;
    sm[t] = v;
    __syncthreads();
    for (int off = 1; off < 1024; off <<= 1) {
        int u = (t >= off) ? sm[t - off] : 0;
        __syncthreads();
        sm[t] += u;
        __syncthreads();
    }
    if (t < nb) bsums[t] = sm[t] - v;  // exclusive
}

__global__ __launch_bounds__(256) void scanC_kernel(const int* __restrict__ counts,
                                                    const int* __restrict__ bsums,
                                                    int* __restrict__ row_ptr, int n, int etot) {
    __shared__ int sm[256];
    int t = threadIdx.x;
    int i = blockIdx.x * 256 + t;
    int v = (i < n) ? counts[i] : 0;
    sm[t] = v;
    __syncthreads();
    for (int off = 1; off < 256; off <<= 1) {
        int u = (t >= off) ? sm[t - off] : 0;
        __syncthreads();
        sm[t] += u;
        __syncthreads();
    }
    if (i < n) row_ptr[i] = bsums[blockIdx.x] + sm[t] - v;
    if (i == 0) row_ptr[n] = etot;
}

// Pass 5: atomic-free scatter, fully coalesced reads.
__global__ __launch_bounds__(256) void scatterB_kernel(const int* __restrict__ src_b,
                                                       const int* __restrict__ pk,
                                                       const int* __restrict__ bstart,
                                                       const int* __restrict__ row_ptr,
                                                       int* __restrict__ csr_src) {
    int part = blockIdx.x & 7, stripe = blockIdx.x >> 3;
    int nstripes = gridDim.x >> 3;
    int b0 = bstart[part], b1 = bstart[part + 1];
    int per = (b1 - b0 + nstripes - 1) / nstripes;
    int e0 = b0 + stripe * per, e1 = min(b1, e0 + per);
    for (int e = e0 + (int)threadIdx.x; e < e1; e += 256) {
        unsigned v = (unsigned)pk[e];
        int d = (int)(v & 131071u);
        int r = (int)(v >> 17);
        csr_src[row_ptr[d] + r] = src_b[e];
    }
}

// ---------------- W1 pre-convert: fp32 [256][64] -> bf16 transposed [64][256] ----------------
__global__ __launch_bounds__(256) void w1cvt_kernel(const float* __restrict__ W1,
                                                    unsigned short* __restrict__ W1t) {
    int t = blockIdx.x * 256 + threadIdx.x;  // 16384 total
    int k = t >> 6, nn = t & 63;
    W1t[(size_t)nn * 256 + k] = bf16_of(W1[t]);
}

// ---------------- Layer 1 GEMM via MFMA, zero LDS: h1(bf16) = x @ W1 ----------------
__global__ __launch_bounds__(256) void gemm1_kernel(const float* __restrict__ x,
                                                    const unsigned short* __restrict__ W1t,
                                                    unsigned short* __restrict__ h1b, int n) {
    int tid = threadIdx.x;
    int w = tid >> 6, lane = tid & 63;
    int p = lane & 15, quad = lane >> 4;
    int r0 = blockIdx.x * 64;
    int row = r0 + 16 * w + p;
    const float* xrow = x + (size_t)row * 256;
    f32x4 z = {0.f, 0.f, 0.f, 0.f};
    f32x4 acc[4] = {z, z, z, z};
#pragma unroll
    for (int kc = 0; kc < 8; ++kc) {
        int k0 = kc * 32 + quad * 8;
        float4 v0 = make_float4(0.f, 0.f, 0.f, 0.f), v1 = v0;
        if (row < n) {
            v0 = *(const float4*)(xrow + k0);
            v1 = *(const float4*)(xrow + k0 + 4);
        }
        union { uint4 u; short8 s; } a;
        a.u = make_uint4(pack_bf2(v0.x, v0.y), pack_bf2(v0.z, v0.w),
                         pack_bf2(v1.x, v1.y), pack_bf2(v1.z, v1.w));
#pragma unroll
        for (int t = 0; t < 4; ++t) {
            short8 b = *(const short8*)(W1t + (size_t)(16 * t + p) * 256 + k0);
            acc[t] = __builtin_amdgcn_mfma_f32_16x16x32_bf16(a.s, b, acc[t], 0, 0, 0);
        }
    }
#pragma unroll
    for (int t = 0; t < 4; ++t)
#pragma unroll
        for (int r = 0; r < 4; ++r) {
            int gr = r0 + 16 * w + quad * 4 + r;
            if (gr < n) h1b[(size_t)gr * 64 + 16 * t + p] = bf16_of(acc[t][r]);
        }
}

// alpha1 from bf16 h1: 8 rows/block (2 rows per wave, 32 lanes each)
__global__ __launch_bounds__(256) void alpha1_kernel(const unsigned short* __restrict__ h1b,
                                                     const float* __restrict__ att_s,
                                                     const float* __restrict__ att_d,
                                                     float* __restrict__ as1,
                                                     float* __restrict__ ad1, int n) {
    int wid = threadIdx.x >> 6, lane = threadIdx.x & 63;
    int p = lane & 31;
    int r = blockIdx.x * 8 + wid * 2 + (lane >> 5);
    if (r >= n) return;
    float2 sc = *(const float2*)(att_s + 2 * p);
    float2 dc = *(const float2*)(att_d + 2 * p);
    float2 h = unpack_bf2(((const unsigned*)h1b)[(size_t)r * 32 + p]);
    float ps = h.x * sc.x + h.y * sc.y;
    float pd = h.x * dc.x + h.y * dc.y;
    ps += __shfl_xor(ps, 1); pd += __shfl_xor(pd, 1);
    ps += __shfl_xor(ps, 2); pd += __shfl_xor(pd, 2);
    if ((p & 3) == 0) {
        as1[(size_t)r * 8 + (p >> 2)] = ps;
        ad1[(size_t)r * 8 + (p >> 2)] = pd;
    }
}

// ---------------- Layer 1 aggregation ----------------
__global__ __launch_bounds__(256) void agg1_kernel(const unsigned short* __restrict__ h1b,
                                                   const float* __restrict__ as1,
                                                   const float* __restrict__ ad1,
                                                   const float* __restrict__ b1,
                                                   const int* __restrict__ row_ptr,
                                                   const int* __restrict__ csr_src,
                                                   float* __restrict__ elu1, int n) {
    int lane = threadIdx.x & 63;
    int node = blockIdx.x * 4 + (threadIdx.x >> 6);
    if (node >= n) return;
    int start = row_ptr[node], end = row_ptr[node + 1];
    int slot = lane >> 3, hd = lane & 7;
    float adh = ad1[(size_t)node * 8 + hd];

    // pass 1: online softmax, (slot,head) layout, 16 edges/iter
    float m = -1e30f, den = 0.f;
    for (int base = start; base < end; base += 64) {
        int nloc = min(64, end - base);
        int eidx = base + lane;
        int sAll = (eidx < end) ? csr_src[eidx] : 0;  // coalesced
        for (int e0 = 0; e0 < nloc; e0 += 16) {
            int s0 = __shfl(sAll, e0 + slot);
            int s1 = __shfl(sAll, e0 + 8 + slot);
            float v0 = lrelu(as1[(size_t)s0 * 8 + hd] + adh);
            float v1 = lrelu(as1[(size_t)s1 * 8 + hd] + adh);
            if (e0 + slot >= nloc) v0 = -INFINITY;
            if (e0 + 8 + slot >= nloc) v1 = -INFINITY;
            float nm = fmaxf(m, fmaxf(v0, v1));
            den = den * __expf(m - nm) + __expf(v0 - nm) + __expf(v1 - nm);
            m = nm;
        }
    }
#pragma unroll
    for (int off = 8; off < 64; off <<= 1) {
        float om = __shfl_xor(m, off);
        float od = __shfl_xor(den, off);
        float nm = fmaxf(m, om);
        den = den * __expf(m - nm) + od * __expf(om - nm);
        m = nm;
    }
    float inv = 1.f / den;

    // pass 2: bf16 gather, channel-pair lanes, 2 edges per gather instr
    int q = lane >> 5, p = lane & 31, hp = p >> 2;
    const unsigned* h1u = (const unsigned*)h1b;  // row stride 32 uints (128B)
    float2 o = make_float2(0.f, 0.f);
    for (int base = start; base < end; base += 64) {
        int nloc = min(64, end - base);
        int eidx = base + lane;
        int sAll = (eidx < end) ? csr_src[eidx] : 0;
        for (int e0 = 0; e0 < nloc; e0 += 8) {
            int s = __shfl(sAll, e0 + slot);
            float v = lrelu(as1[(size_t)s * 8 + hd] + adh);
            float w = (e0 + slot < nloc) ? __expf(v - m) * inv : 0.f;
#pragma unroll
            for (int j = 0; j < 8; j += 2) {
                int sj = __shfl(s, (j + q) * 8);
                float wj = __shfl(w, (j + q) * 8 + hp);
                float2 hf = unpack_bf2(h1u[(size_t)sj * 32 + p]);
                o.x = fmaf(hf.x, wj, o.x);
                o.y = fmaf(hf.y, wj, o.y);
            }
        }
    }
    o.x += __shfl_xor(o.x, 32);
    o.y += __shfl_xor(o.y, 32);
    if (lane < 32) {
        float2 bb = *(const float2*)(b1 + 2 * p);
        float v0 = o.x + bb.x, v1 = o.y + bb.y;
        v0 = v0 > 0.f ? v0 : __expf(v0) - 1.f;
        v1 = v1 > 0.f ? v1 : __expf(v1) - 1.f;
        *(float2*)(elu1 + (size_t)node * 64 + 2 * p) = make_float2(v0, v1);
    }
}

// ---------------- Layer 2 GEMM: h2(bf16) = elu1 @ W2, fused alpha2 ----------------
__global__ __launch_bounds__(256) void gemm2_kernel(const float* __restrict__ elu1,
                                                    const float* __restrict__ W2,
                                                    const float* __restrict__ att_s,
                                                    const float* __restrict__ att_d,
                                                    unsigned short* __restrict__ h2b,
                                                    float* __restrict__ as2,
                                                    float* __restrict__ ad2, int n) {
    __shared__ float As[64][132];
    __shared__ float Bs[64][40];
    int tid = threadIdx.x;
    int r0 = blockIdx.x * 128;
    int cx = tid & 7, ry = tid >> 3;
    float sa[5], da[5];
#pragma unroll
    for (int j = 0; j < 5; ++j) {
        sa[j] = att_s[5 * cx + j];
        da[j] = att_d[5 * cx + j];
    }
    for (int t = tid; t < 640; t += 256) {
        int k = t / 10, cq = t % 10;
        *(float4*)&Bs[k][4 * cq] = *(const float4*)(W2 + (size_t)k * 40 + 4 * cq);
    }
    for (int t = tid; t < 2048; t += 256) {
        int row = t >> 4, kq = t & 15;
        int gr = r0 + row;
        float4 av = make_float4(0.f, 0.f, 0.f, 0.f);
        if (gr < n) av = *(const float4*)(elu1 + (size_t)gr * 64 + 4 * kq);
        As[4 * kq + 0][row] = av.x;
        As[4 * kq + 1][row] = av.y;
        As[4 * kq + 2][row] = av.z;
        As[4 * kq + 3][row] = av.w;
    }
    __syncthreads();
    float acc[4][5] = {{0.f}};
#pragma unroll 8
    for (int k = 0; k < 64; ++k) {
        float4 a = *(const float4*)&As[k][4 * ry];
        float ar[4] = {a.x, a.y, a.z, a.w};
        float br[5];
#pragma unroll
        for (int j = 0; j < 5; ++j) br[j] = Bs[k][5 * cx + j];
#pragma unroll
        for (int i = 0; i < 4; ++i)
#pragma unroll
            for (int j = 0; j < 5; ++j) acc[i][j] = fmaf(ar[i], br[j], acc[i][j]);
    }
#pragma unroll
    for (int i = 0; i < 4; ++i) {
        int gr = r0 + 4 * ry + i;
        float ps = 0.f, pd = 0.f;
#pragma unroll
        for (int j = 0; j < 5; ++j) {
            ps = fmaf(acc[i][j], sa[j], ps);
            pd = fmaf(acc[i][j], da[j], pd);
        }
        ps += __shfl_xor(ps, 1); pd += __shfl_xor(pd, 1);
        ps += __shfl_xor(ps, 2); pd += __shfl_xor(pd, 2);
        ps += __shfl_xor(ps, 4); pd += __shfl_xor(pd, 4);
        if (gr < n) {
#pragma unroll
            for (int j = 0; j < 5; ++j) h2b[(size_t)gr * 40 + 5 * cx + j] = bf16_of(acc[i][j]);
            if (cx == 0) {
                as2[gr] = ps;
                ad2[gr] = pd;
            }
        }
    }
}

// ---------------- Layer 2 aggregation + bias + log_softmax ----------------
__global__ __launch_bounds__(256) void agg2_kernel(const unsigned short* __restrict__ h2b,
                                                   const float* __restrict__ as2,
                                                   const float* __restrict__ ad2,
                                                   const float* __restrict__ b2,
                                                   const int* __restrict__ row_ptr,
                                                   const int* __restrict__ csr_src,
                                                   float* __restrict__ out, int n) {
    int lane = threadIdx.x & 63;
    int node = blockIdx.x * 4 + (threadIdx.x >> 6);
    if (node >= n) return;
    int start = row_ptr[node], end = row_ptr[node + 1];
    float adn = ad2[node];

    float m = -1e30f, den = 0.f;
    for (int base = start; base < end; base += 64) {
        int eidx = base + lane;
        bool valid = eidx < end;
        int s = valid ? csr_src[eidx] : 0;
        float v = lrelu(as2[s] + adn);
        if (!valid) v = -INFINITY;
        float nm = fmaxf(m, v);
        den = den * __expf(m - nm) + __expf(v - nm);
        m = nm;
    }
#pragma unroll
    for (int off = 1; off < 64; off <<= 1) {
        float om = __shfl_xor(m, off);
        float od = __shfl_xor(den, off);
        float nm = fmaxf(m, om);
        den = den * __expf(m - nm) + od * __expf(om - nm);
        m = nm;
    }
    float inv = 1.f / den;

    int q = lane >> 5, p = lane & 31;
    int pc = min(p, 19);
    const unsigned* h2u = (const unsigned*)h2b;  // row stride 20 uints (80B)
    float2 o = make_float2(0.f, 0.f);
    for (int base = start; base < end; base += 64) {
        int nloc = min(64, end - base);
        int eidx = base + lane;
        bool valid = eidx < end;
        int sAll = valid ? csr_src[eidx] : 0;
        float v = lrelu(as2[sAll] + adn);
        float w = valid ? __expf(v - m) * inv : 0.f;
        for (int g = 0; g < nloc; g += 8) {
#pragma unroll
            for (int j = 0; j < 8; j += 2) {
                int idx = g + j + q;
                int sj = __shfl(sAll, idx);
                float wj = __shfl(w, idx);
                float2 hf = unpack_bf2(h2u[(size_t)sj * 20 + pc]);
                o.x = fmaf(hf.x, wj, o.x);
                o.y = fmaf(hf.y, wj, o.y);
            }
        }
    }
    o.x += __shfl_xor(o.x, 32);
    o.y += __shfl_xor(o.y, 32);
    bool act = (lane < 32) && (p < 20);
    float v0 = -1e30f, v1 = -1e30f;
    if (act) {
        float2 bb = *(const float2*)(b2 + 2 * p);
        v0 = o.x + bb.x;
        v1 = o.y + bb.y;
    }
    float vm = fmaxf(v0, v1);
#pragma unroll
    for (int off = 1; off < 64; off <<= 1) vm = fmaxf(vm, __shfl_xor(vm, off));
    float ex = act ? (__expf(v0 - vm) + __expf(v1 - vm)) : 0.f;
#pragma unroll
    for (int off = 1; off < 64; off <<= 1) ex += __shfl_xor(ex, off);
    if (act) {
        float lg = __logf(ex);
        *(float2*)(out + (size_t)node * 40 + 2 * p) = make_float2(v0 - vm - lg, v1 - vm - lg);
    }
}

// ---------------- launch ----------------
extern "C" void kernel_launch(void* const* d_in, const int* in_sizes, int n_in,
                              void* d_out, int out_size, void* d_ws, size_t ws_size,
                              hipStream_t stream) {
    const float* x        = (const float*)d_in[0];
    const float* W1       = (const float*)d_in[1];
    const float* att_src1 = (const float*)d_in[2];
    const float* att_dst1 = (const float*)d_in[3];
    const float* b1       = (const float*)d_in[4];
    const float* W2       = (const float*)d_in[5];
    const float* att_src2 = (const float*)d_in[6];
    const float* att_dst2 = (const float*)d_in[7];
    const float* b2       = (const float*)d_in[8];
    const int*   ei       = (const int*)d_in[9];

    int n    = in_sizes[0] / 256;   // 100000
    int etot = in_sizes[9] / 2;     // 1700000
    const int* srcp = ei;
    const int* dstp = ei + etot;

    char* ws = (char*)d_ws;
    size_t off = 0;
    unsigned short* h1b = (unsigned short*)(ws + off); off += (size_t)n * 64 * 2;
    unsigned short* h2b = (unsigned short*)(ws + off); off += (size_t)n * 40 * 2;
    unsigned short* W1t = (unsigned short*)(ws + off); off += (size_t)64 * 256 * 2;
    float* elu1 = (float*)(ws + off); off += (size_t)n * 64 * 4;
    float* as1  = (float*)(ws + off); off += (size_t)n * 8 * 4;
    float* ad1  = (float*)(ws + off); off += (size_t)n * 8 * 4;
    float* as2  = (float*)(ws + off); off += (size_t)n * 4;
    float* ad2  = (float*)(ws + off); off += (size_t)n * 4;
    int* row_ptr = (int*)(ws + off); off += (size_t)(n + 64) * 4;
    int* counts  = (int*)(ws + off); off += (size_t)n * 4;
    int* bsums   = (int*)(ws + off); off += (size_t)2048 * 4;
    int* csr_src = (int*)(ws + off); off += (size_t)etot * 4;
    int* blk_cnt = (int*)(ws + off); off += (size_t)1024 * 8 * 4;
    int* blk_base= (int*)(ws + off); off += (size_t)1024 * 8 * 4;
    int* bstart  = (int*)(ws + off); off += (size_t)16 * 4;
    float* outp = (float*)d_out;

    // bucket staging arrays alias elu1 (3*etot*4 = 20.4MB <= n*64*4 = 25.6MB);
    // elu1 is only written by agg1, after scatterB completes (stream-ordered).
    int* src_b = (int*)elu1;
    int* dst_b = src_b + etot;
    int* pk    = dst_b + etot;

    int psz = (n + 7) >> 3;
    int chunk = (etot + 1023) / 1024;

    hipMemsetAsync(counts, 0, (size_t)n * 4, stream);
    int nb256 = (n + 255) / 256;
    bcount_kernel<<<1024, 256, 0, stream>>>(dstp, blk_cnt, etot, psz, chunk);
    bscan_kernel<<<1, 1024, 0, stream>>>(blk_cnt, blk_base, bstart);
    bscatter_kernel<<<1024, 256, 0, stream>>>(srcp, dstp, blk_base, src_b, dst_b, etot, psz, chunk);
    histB_kernel<<<2048, 256, 0, stream>>>(dst_b, bstart, counts, pk);
    scanA_kernel<<<nb256, 256, 0, stream>>>(counts, bsums, n);
    scanB_kernel<<<1, 1024, 0, stream>>>(bsums, nb256);
    scanC_kernel<<<nb256, 256, 0, stream>>>(counts, bsums, row_ptr, n, etot);
    scatterB_kernel<<<2048, 256, 0, stream>>>(src_b, pk, bstart, row_ptr, csr_src);

    int nb4 = (n + 3) / 4;
    w1cvt_kernel<<<64, 256, 0, stream>>>(W1, W1t);
    gemm1_kernel<<<(n + 63) / 64, 256, 0, stream>>>(x, W1t, h1b, n);
    alpha1_kernel<<<(n + 7) / 8, 256, 0, stream>>>(h1b, att_src1, att_dst1, as1, ad1, n);
    agg1_kernel<<<nb4, 256, 0, stream>>>(h1b, as1, ad1, b1, row_ptr, csr_src, elu1, n);
    gemm2_kernel<<<(n + 127) / 128, 256, 0, stream>>>(elu1, W2, att_src2, att_dst2, h2b, as2, ad2, n);
    agg2_kernel<<<nb4, 256, 0, stream>>>(h2b, as2, ad2, b2, row_ptr, csr_src, outp, n);
}

// Round 2
// 439.027 us; speedup vs baseline: 1.1222x; 1.0467x over previous
//
#include <hip/hip_runtime.h>
#include <hip/hip_bf16.h>

#define NEG_SLOPE 0.2f

typedef __attribute__((ext_vector_type(8))) short short8;
typedef __attribute__((ext_vector_type(4))) float f32x4;

__device__ __forceinline__ float lrelu(float x) { return x >= 0.f ? x : NEG_SLOPE * x; }

// pack two fp32 -> bf16x2 (RNE), low = a, high = b
__device__ __forceinline__ unsigned pack_bf2(float a, float b) {
    unsigned ua = __float_as_uint(a), ub = __float_as_uint(b);
    ua = (ua + 0x7fffu + ((ua >> 16) & 1u)) >> 16;
    ub = (ub + 0x7fffu + ((ub >> 16) & 1u)) & 0xffff0000u;
    return ua | ub;
}
__device__ __forceinline__ float2 unpack_bf2(unsigned u) {
    return make_float2(__uint_as_float(u << 16), __uint_as_float(u & 0xffff0000u));
}
__device__ __forceinline__ unsigned short bf16_of(float a) {
    unsigned ua = __float_as_uint(a);
    return (unsigned short)((ua + 0x7fffu + ((ua >> 16) & 1u)) >> 16);
}

// ---------------- CSR build (round-6: deterministic XCD bucketing, single-read passes) ----------------
// Pass 1: per-block histogram of 8 XCD partitions.
__global__ __launch_bounds__(256) void bcount_kernel(const int* __restrict__ dst,
                                                     int* __restrict__ blk_cnt,
                                                     int etot, int psz, int chunk) {
    __shared__ int cnt[8];
    if (threadIdx.x < 8) cnt[threadIdx.x] = 0;
    __syncthreads();
    int e0 = blockIdx.x * chunk, e1 = min(etot, e0 + chunk);
    for (int e = e0 + (int)threadIdx.x; e < e1; e += 256) {
        int p = min(dst[e] / psz, 7);
        atomicAdd(&cnt[p], 1);
    }
    __syncthreads();
    if (threadIdx.x < 8) blk_cnt[blockIdx.x * 8 + threadIdx.x] = cnt[threadIdx.x];
}

// Pass 2: scan 1024 block-counts per bucket + cross-bucket bases. One block, 1024 threads.
__global__ __launch_bounds__(1024) void bscan_kernel(const int* __restrict__ blk_cnt,
                                                     int* __restrict__ blk_base,
                                                     int* __restrict__ bstart) {
    __shared__ int wsum[16];
    __shared__ int coltot[8];
    __shared__ int colbase[9];
    int t = threadIdx.x;
    int lane = t & 63, wid = t >> 6;
    int v[8], incl[8];
#pragma unroll
    for (int p = 0; p < 8; ++p) v[p] = blk_cnt[t * 8 + p];
#pragma unroll
    for (int p = 0; p < 8; ++p) {
        int x = v[p];
#pragma unroll
        for (int off = 1; off < 64; off <<= 1) {
            int y = __shfl_up(x, off);
            if (lane >= off) x += y;
        }
        if (lane == 63) wsum[wid] = x;
        __syncthreads();
        if (wid == 0) {
            int s = (lane < 16) ? wsum[lane] : 0;
#pragma unroll
            for (int off = 1; off < 16; off <<= 1) {
                int y = __shfl_up(s, off);
                if (lane >= off) s += y;
            }
            if (lane < 16) wsum[lane] = s;
        }
        __syncthreads();
        int base = (wid > 0) ? wsum[wid - 1] : 0;
        incl[p] = base + x;
        if (t == 1023) coltot[p] = incl[p];
        __syncthreads();
    }
    if (t == 0) {
        int acc = 0;
        for (int p = 0; p < 8; ++p) {
            colbase[p] = acc;
            bstart[p] = acc;
            acc += coltot[p];
        }
        colbase[8] = acc;
        bstart[8] = acc;
    }
    __syncthreads();
#pragma unroll
    for (int p = 0; p < 8; ++p) blk_base[t * 8 + p] = colbase[p] + incl[p] - v[p];
}

// Pass 3: scatter edges into per-partition contiguous lists (deterministic bases, LDS ranks).
__global__ __launch_bounds__(256) void bscatter_kernel(const int* __restrict__ src,
                                                       const int* __restrict__ dst,
                                                       const int* __restrict__ blk_base,
                                                       int* __restrict__ src_b,
                                                       int* __restrict__ dst_b,
                                                       int etot, int psz, int chunk) {
    __shared__ int base[8];
    __shared__ int lcnt[8];
    if (threadIdx.x < 8) {
        base[threadIdx.x] = blk_base[blockIdx.x * 8 + threadIdx.x];
        lcnt[threadIdx.x] = 0;
    }
    __syncthreads();
    int e0 = blockIdx.x * chunk, e1 = min(etot, e0 + chunk);
    for (int e = e0 + (int)threadIdx.x; e < e1; e += 256) {
        int d = dst[e], s = src[e];
        int p = min(d / psz, 7);
        int loc = atomicAdd(&lcnt[p], 1);
        int pos = base[p] + loc;
        dst_b[pos] = d;
        src_b[pos] = s;
    }
}

// Pass 4: degree histogram over bucketed list (XCD-local atomics), emit packed (dst | rank<<17).
__global__ __launch_bounds__(256) void histB_kernel(const int* __restrict__ dst_b,
                                                    const int* __restrict__ bstart,
                                                    int* __restrict__ counts,
                                                    int* __restrict__ pk) {
    int part = blockIdx.x & 7, stripe = blockIdx.x >> 3;
    int nstripes = gridDim.x >> 3;
    int b0 = bstart[part], b1 = bstart[part + 1];
    int per = (b1 - b0 + nstripes - 1) / nstripes;
    int e0 = b0 + stripe * per, e1 = min(b1, e0 + per);
    for (int e = e0 + (int)threadIdx.x; e < e1; e += 256) {
        int d = dst_b[e];
        int r = atomicAdd(&counts[d], 1);
        pk[e] = d | (r << 17);
    }
}

__global__ __launch_bounds__(256) void scanA_kernel(const int* __restrict__ counts,
                                                    int* __restrict__ bsums, int n) {
    __shared__ int sm[256];
    int i = blockIdx.x * 256 + threadIdx.x;
    sm[threadIdx.x] = (i < n) ? counts[i] : 0;
    __syncthreads();
    for (int off = 128; off > 0; off >>= 1) {
        if (threadIdx.x < off) sm[threadIdx.x] += sm[threadIdx.x + off];
        __syncthreads();
    }
    if (threadIdx.x == 0) bsums[blockIdx.x] = sm[0];
}

__global__ __launch_bounds__(1024) void scanB_kernel(int* __restrict__ bsums, int nb) {
    __shared__ int sm[1024];
    int t = threadIdx.x;
    int v = (t < nb) ? bsums[t] : 0;
    sm[t] = v;
    __syncthreads();
    for (int off = 1; off < 1024; off <<= 1) {
        int u = (t >= off) ? sm[t - off] : 0;
        __syncthreads();
        sm[t] += u;
        __syncthreads();
    }
    if (t < nb) bsums[t] = sm[t] - v;  // exclusive
}

__global__ __launch_bounds__(256) void scanC_kernel(const int* __restrict__ counts,
                                                    const int* __restrict__ bsums,
                                                    int* __restrict__ row_ptr, int n, int etot) {
    __shared__ int sm[256];
    int t = threadIdx.x;
    int i = blockIdx.x * 256 + t;
    int v = (i < n) ? counts[i] : 0;
    sm[t] = v;
    __syncthreads();
    for (int off = 1; off < 256; off <<= 1) {
        int u = (t >= off) ? sm[t - off] : 0;
        __syncthreads();
        sm[t] += u;
        __syncthreads();
    }
    if (i < n) row_ptr[i] = bsums[blockIdx.x] + sm[t] - v;
    if (i == 0) row_ptr[n] = etot;
}

// Pass 5: atomic-free scatter, fully coalesced reads.
__global__ __launch_bounds__(256) void scatterB_kernel(const int* __restrict__ src_b,
                                                       const int* __restrict__ pk,
                                                       const int* __restrict__ bstart,
                                                       const int* __restrict__ row_ptr,
                                                       int* __restrict__ csr_src) {
    int part = blockIdx.x & 7, stripe = blockIdx.x >> 3;
    int nstripes = gridDim.x >> 3;
    int b0 = bstart[part], b1 = bstart[part + 1];
    int per = (b1 - b0 + nstripes - 1) / nstripes;
    int e0 = b0 + stripe * per, e1 = min(b1, e0 + per);
    for (int e = e0 + (int)threadIdx.x; e < e1; e += 256) {
        unsigned v = (unsigned)pk[e];
        int d = (int)(v & 131071u);
        int r = (int)(v >> 17);
        csr_src[row_ptr[d] + r] = src_b[e];
    }
}

// ---------------- W1 pre-convert: fp32 [256][64] -> bf16 transposed [64][256] ----------------
__global__ __launch_bounds__(256) void w1cvt_kernel(const float* __restrict__ W1,
                                                    unsigned short* __restrict__ W1t) {
    int t = blockIdx.x * 256 + threadIdx.x;  // 16384 total
    int k = t >> 6, nn = t & 63;
    W1t[(size_t)nn * 256 + k] = bf16_of(W1[t]);
}

// ---------------- Layer 1 GEMM via MFMA, zero LDS: h1(bf16) = x @ W1 ----------------
__global__ __launch_bounds__(256) void gemm1_kernel(const float* __restrict__ x,
                                                    const unsigned short* __restrict__ W1t,
                                                    unsigned short* __restrict__ h1b, int n) {
    int tid = threadIdx.x;
    int w = tid >> 6, lane = tid & 63;
    int p = lane & 15, quad = lane >> 4;
    int r0 = blockIdx.x * 64;
    int row = r0 + 16 * w + p;
    const float* xrow = x + (size_t)row * 256;
    f32x4 z = {0.f, 0.f, 0.f, 0.f};
    f32x4 acc[4] = {z, z, z, z};
#pragma unroll
    for (int kc = 0; kc < 8; ++kc) {
        int k0 = kc * 32 + quad * 8;
        float4 v0 = make_float4(0.f, 0.f, 0.f, 0.f), v1 = v0;
        if (row < n) {
            v0 = *(const float4*)(xrow + k0);
            v1 = *(const float4*)(xrow + k0 + 4);
        }
        union { uint4 u; short8 s; } a;
        a.u = make_uint4(pack_bf2(v0.x, v0.y), pack_bf2(v0.z, v0.w),
                         pack_bf2(v1.x, v1.y), pack_bf2(v1.z, v1.w));
#pragma unroll
        for (int t = 0; t < 4; ++t) {
            short8 b = *(const short8*)(W1t + (size_t)(16 * t + p) * 256 + k0);
            acc[t] = __builtin_amdgcn_mfma_f32_16x16x32_bf16(a.s, b, acc[t], 0, 0, 0);
        }
    }
#pragma unroll
    for (int t = 0; t < 4; ++t)
#pragma unroll
        for (int r = 0; r < 4; ++r) {
            int gr = r0 + 16 * w + quad * 4 + r;
            if (gr < n) h1b[(size_t)gr * 64 + 16 * t + p] = bf16_of(acc[t][r]);
        }
}

// alpha1 from bf16 h1: 8 rows/block (2 rows per wave, 32 lanes each)
__global__ __launch_bounds__(256) void alpha1_kernel(const unsigned short* __restrict__ h1b,
                                                     const float* __restrict__ att_s,
                                                     const float* __restrict__ att_d,
                                                     float* __restrict__ as1,
                                                     float* __restrict__ ad1, int n) {
    int wid = threadIdx.x >> 6, lane = threadIdx.x & 63;
    int p = lane & 31;
    int r = blockIdx.x * 8 + wid * 2 + (lane >> 5);
    if (r >= n) return;
    float2 sc = *(const float2*)(att_s + 2 * p);
    float2 dc = *(const float2*)(att_d + 2 * p);
    float2 h = unpack_bf2(((const unsigned*)h1b)[(size_t)r * 32 + p]);
    float ps = h.x * sc.x + h.y * sc.y;
    float pd = h.x * dc.x + h.y * dc.y;
    ps += __shfl_xor(ps, 1); pd += __shfl_xor(pd, 1);
    ps += __shfl_xor(ps, 2); pd += __shfl_xor(pd, 2);
    if ((p & 3) == 0) {
        as1[(size_t)r * 8 + (p >> 2)] = ps;
        ad1[(size_t)r * 8 + (p >> 2)] = pd;
    }
}

// ---------------- Layer 1 aggregation: SINGLE-PASS (shift-free softmax) ----------------
// v = lrelu(alpha_src+alpha_dst) is bounded (|v| <~ 2), so exp(v) cannot overflow:
// out = (sum_e exp(v_e) h[src_e]) / (sum_e exp(v_e)) needs no max subtraction.
__global__ __launch_bounds__(256) void agg1_kernel(const unsigned short* __restrict__ h1b,
                                                   const float* __restrict__ as1,
                                                   const float* __restrict__ ad1,
                                                   const float* __restrict__ b1,
                                                   const int* __restrict__ row_ptr,
                                                   const int* __restrict__ csr_src,
                                                   float* __restrict__ elu1, int n) {
    int lane = threadIdx.x & 63;
    int node = blockIdx.x * 4 + (threadIdx.x >> 6);
    if (node >= n) return;
    int start = row_ptr[node], end = row_ptr[node + 1];
    int slot = lane >> 3, hd = lane & 7;
    float adh = ad1[(size_t)node * 8 + hd];
    int q = lane >> 5, p = lane & 31, hp = p >> 2;
    const unsigned* h1u = (const unsigned*)h1b;  // row stride 32 uints (128B)
    float2 o = make_float2(0.f, 0.f);
    float den = 0.f;
    for (int base = start; base < end; base += 64) {
        int nloc = min(64, end - base);
        int eidx = base + lane;
        int sAll = (eidx < end) ? csr_src[eidx] : 0;  // coalesced
        for (int e0 = 0; e0 < nloc; e0 += 8) {
            // weight for edge e0+slot, head hd (8 edges x 8 heads across the wave)
            int s = __shfl(sAll, e0 + slot);
            float v = lrelu(as1[(size_t)s * 8 + hd] + adh);
            float w = (e0 + slot < nloc) ? __expf(v) : 0.f;
            den += w;
            // weighted gather: lane (q,p) = channel pair 2p..2p+1, edges j+q
#pragma unroll
            for (int j = 0; j < 8; j += 2) {
                int sj = __shfl(s, (j + q) * 8);
                float wj = __shfl(w, (j + q) * 8 + hp);
                float2 hf = unpack_bf2(h1u[(size_t)sj * 32 + p]);
                o.x = fmaf(hf.x, wj, o.x);
                o.y = fmaf(hf.y, wj, o.y);
            }
        }
    }
    // den is per (slot,hd): reduce over slot bits (3,4,5) so den[hd] is wave-wide
    den += __shfl_xor(den, 8);
    den += __shfl_xor(den, 16);
    den += __shfl_xor(den, 32);
    float inv = 1.f / __shfl(den, hp);  // lane hp holds hd==hp
    o.x += __shfl_xor(o.x, 32);
    o.y += __shfl_xor(o.y, 32);
    if (lane < 32) {
        float2 bb = *(const float2*)(b1 + 2 * p);
        float v0 = o.x * inv + bb.x, v1 = o.y * inv + bb.y;
        v0 = v0 > 0.f ? v0 : __expf(v0) - 1.f;
        v1 = v1 > 0.f ? v1 : __expf(v1) - 1.f;
        *(float2*)(elu1 + (size_t)node * 64 + 2 * p) = make_float2(v0, v1);
    }
}

// ---------------- Layer 2 GEMM: h2(bf16) = elu1 @ W2, fused alpha2 ----------------
__global__ __launch_bounds__(256) void gemm2_kernel(const float* __restrict__ elu1,
                                                    const float* __restrict__ W2,
                                                    const float* __restrict__ att_s,
                                                    const float* __restrict__ att_d,
                                                    unsigned short* __restrict__ h2b,
                                                    float* __restrict__ as2,
                                                    float* __restrict__ ad2, int n) {
    __shared__ float As[64][132];
    __shared__ float Bs[64][40];
    int tid = threadIdx.x;
    int r0 = blockIdx.x * 128;
    int cx = tid & 7, ry = tid >> 3;
    float sa[5], da[5];
#pragma unroll
    for (int j = 0; j < 5; ++j) {
        sa[j] = att_s[5 * cx + j];
        da[j] = att_d[5 * cx + j];
    }
    for (int t = tid; t < 640; t += 256) {
        int k = t / 10, cq = t % 10;
        *(float4*)&Bs[k][4 * cq] = *(const float4*)(W2 + (size_t)k * 40 + 4 * cq);
    }
    for (int t = tid; t < 2048; t += 256) {
        int row = t >> 4, kq = t & 15;
        int gr = r0 + row;
        float4 av = make_float4(0.f, 0.f, 0.f, 0.f);
        if (gr < n) av = *(const float4*)(elu1 + (size_t)gr * 64 + 4 * kq);
        As[4 * kq + 0][row] = av.x;
        As[4 * kq + 1][row] = av.y;
        As[4 * kq + 2][row] = av.z;
        As[4 * kq + 3][row] = av.w;
    }
    __syncthreads();
    float acc[4][5] = {{0.f}};
#pragma unroll 8
    for (int k = 0; k < 64; ++k) {
        float4 a = *(const float4*)&As[k][4 * ry];
        float ar[4] = {a.x, a.y, a.z, a.w};
        float br[5];
#pragma unroll
        for (int j = 0; j < 5; ++j) br[j] = Bs[k][5 * cx + j];
#pragma unroll
        for (int i = 0; i < 4; ++i)
#pragma unroll
            for (int j = 0; j < 5; ++j) acc[i][j] = fmaf(ar[i], br[j], acc[i][j]);
    }
#pragma unroll
    for (int i = 0; i < 4; ++i) {
        int gr = r0 + 4 * ry + i;
        float ps = 0.f, pd = 0.f;
#pragma unroll
        for (int j = 0; j < 5; ++j) {
            ps = fmaf(acc[i][j], sa[j], ps);
            pd = fmaf(acc[i][j], da[j], pd);
        }
        ps += __shfl_xor(ps, 1); pd += __shfl_xor(pd, 1);
        ps += __shfl_xor(ps, 2); pd += __shfl_xor(pd, 2);
        ps += __shfl_xor(ps, 4); pd += __shfl_xor(pd, 4);
        if (gr < n) {
#pragma unroll
            for (int j = 0; j < 5; ++j) h2b[(size_t)gr * 40 + 5 * cx + j] = bf16_of(acc[i][j]);
            if (cx == 0) {
                as2[gr] = ps;
                ad2[gr] = pd;
            }
        }
    }
}

// ---------------- Layer 2 aggregation (single-pass) + bias + log_softmax ----------------
__global__ __launch_bounds__(256) void agg2_kernel(const unsigned short* __restrict__ h2b,
                                                   const float* __restrict__ as2,
                                                   const float* __restrict__ ad2,
                                                   const float* __restrict__ b2,
                                                   const int* __restrict__ row_ptr,
                                                   const int* __restrict__ csr_src,
                                                   float* __restrict__ out, int n) {
    int lane = threadIdx.x & 63;
    int node = blockIdx.x * 4 + (threadIdx.x >> 6);
    if (node >= n) return;
    int start = row_ptr[node], end = row_ptr[node + 1];
    float adn = ad2[node];

    int q = lane >> 5, p = lane & 31;
    int pc = min(p, 19);
    const unsigned* h2u = (const unsigned*)h2b;  // row stride 20 uints (80B)
    float2 o = make_float2(0.f, 0.f);
    float den = 0.f;
    for (int base = start; base < end; base += 64) {
        int nloc = min(64, end - base);
        int eidx = base + lane;
        bool valid = eidx < end;
        int sAll = valid ? csr_src[eidx] : 0;
        float v = lrelu(as2[sAll] + adn);
        float w = valid ? __expf(v) : 0.f;
        den += w;
        for (int g = 0; g < nloc; g += 8) {
#pragma unroll
            for (int j = 0; j < 8; j += 2) {
                int idx = g + j + q;
                int sj = __shfl(sAll, idx);
                float wj = __shfl(w, idx);
                float2 hf = unpack_bf2(h2u[(size_t)sj * 20 + pc]);
                o.x = fmaf(hf.x, wj, o.x);
                o.y = fmaf(hf.y, wj, o.y);
            }
        }
    }
#pragma unroll
    for (int off = 1; off < 64; off <<= 1) den += __shfl_xor(den, off);
    float inv = 1.f / den;
    o.x += __shfl_xor(o.x, 32);
    o.y += __shfl_xor(o.y, 32);
    bool act = (lane < 32) && (p < 20);
    float v0 = -1e30f, v1 = -1e30f;
    if (act) {
        float2 bb = *(const float2*)(b2 + 2 * p);
        v0 = o.x * inv + bb.x;
        v1 = o.y * inv + bb.y;
    }
    float vm = fmaxf(v0, v1);
#pragma unroll
    for (int off = 1; off < 64; off <<= 1) vm = fmaxf(vm, __shfl_xor(vm, off));
    float ex = act ? (__expf(v0 - vm) + __expf(v1 - vm)) : 0.f;
#pragma unroll
    for (int off = 1; off < 64; off <<= 1) ex += __shfl_xor(ex, off);
    if (act) {
        float lg = __logf(ex);
        *(float2*)(out + (size_t)node * 40 + 2 * p) = make_float2(v0 - vm - lg, v1 - vm - lg);
    }
}

// ---------------- launch ----------------
extern "C" void kernel_launch(void* const* d_in, const int* in_sizes, int n_in,
                              void* d_out, int out_size, void* d_ws, size_t ws_size,
                              hipStream_t stream) {
    const float* x        = (const float*)d_in[0];
    const float* W1       = (const float*)d_in[1];
    const float* att_src1 = (const float*)d_in[2];
    const float* att_dst1 = (const float*)d_in[3];
    const float* b1       = (const float*)d_in[4];
    const float* W2       = (const float*)d_in[5];
    const float* att_src2 = (const float*)d_in[6];
    const float* att_dst2 = (const float*)d_in[7];
    const float* b2       = (const float*)d_in[8];
    const int*   ei       = (const int*)d_in[9];

    int n    = in_sizes[0] / 256;   // 100000
    int etot = in_sizes[9] / 2;     // 1700000
    const int* srcp = ei;
    const int* dstp = ei + etot;

    char* ws = (char*)d_ws;
    size_t off = 0;
    unsigned short* h1b = (unsigned short*)(ws + off); off += (size_t)n * 64 * 2;
    unsigned short* h2b = (unsigned short*)(ws + off); off += (size_t)n * 40 * 2;
    unsigned short* W1t = (unsigned short*)(ws + off); off += (size_t)64 * 256 * 2;
    float* elu1 = (float*)(ws + off); off += (size_t)n * 64 * 4;
    float* as1  = (float*)(ws + off); off += (size_t)n * 8 * 4;
    float* ad1  = (float*)(ws + off); off += (size_t)n * 8 * 4;
    float* as2  = (float*)(ws + off); off += (size_t)n * 4;
    float* ad2  = (float*)(ws + off); off += (size_t)n * 4;
    int* row_ptr = (int*)(ws + off); off += (size_t)(n + 64) * 4;
    int* counts  = (int*)(ws + off); off += (size_t)n * 4;
    int* bsums   = (int*)(ws + off); off += (size_t)2048 * 4;
    int* csr_src = (int*)(ws + off); off += (size_t)etot * 4;
    int* blk_cnt = (int*)(ws + off); off += (size_t)1024 * 8 * 4;
    int* blk_base= (int*)(ws + off); off += (size_t)1024 * 8 * 4;
    int* bstart  = (int*)(ws + off); off += (size_t)16 * 4;
    float* outp = (float*)d_out;

    // bucket staging arrays alias elu1 (3*etot*4 = 20.4MB <= n*64*4 = 25.6MB);
    // elu1 is only written by agg1, after scatterB completes (stream-ordered).
    int* src_b = (int*)elu1;
    int* dst_b = src_b + etot;
    int* pk    = dst_b + etot;

    int psz = (n + 7) >> 3;
    int chunk = (etot + 1023) / 1024;

    hipMemsetAsync(counts, 0, (size_t)n * 4, stream);
    int nb256 = (n + 255) / 256;
    bcount_kernel<<<1024, 256, 0, stream>>>(dstp, blk_cnt, etot, psz, chunk);
    bscan_kernel<<<1, 1024, 0, stream>>>(blk_cnt, blk_base, bstart);
    bscatter_kernel<<<1024, 256, 0, stream>>>(srcp, dstp, blk_base, src_b, dst_b, etot, psz, chunk);
    histB_kernel<<<2048, 256, 0, stream>>>(dst_b, bstart, counts, pk);
    scanA_kernel<<<nb256, 256, 0, stream>>>(counts, bsums, n);
    scanB_kernel<<<1, 1024, 0, stream>>>(bsums, nb256);
    scanC_kernel<<<nb256, 256, 0, stream>>>(counts, bsums, row_ptr, n, etot);
    scatterB_kernel<<<2048, 256, 0, stream>>>(src_b, pk, bstart, row_ptr, csr_src);

    int nb4 = (n + 3) / 4;
    w1cvt_kernel<<<64, 256, 0, stream>>>(W1, W1t);
    gemm1_kernel<<<(n + 63) / 64, 256, 0, stream>>>(x, W1t, h1b, n);
    alpha1_kernel<<<(n + 7) / 8, 256, 0, stream>>>(h1b, att_src1, att_dst1, as1, ad1, n);
    agg1_kernel<<<nb4, 256, 0, stream>>>(h1b, as1, ad1, b1, row_ptr, csr_src, elu1, n);
    gemm2_kernel<<<(n + 127) / 128, 256, 0, stream>>>(elu1, W2, att_src2, att_dst2, h2b, as2, ad2, n);
    agg2_kernel<<<nb4, 256, 0, stream>>>(h2b, as2, ad2, b2, row_ptr, csr_src, outp, n);
}

// Round 3
// 388.102 us; speedup vs baseline: 1.2694x; 1.1312x over previous
//
#include <hip/hip_runtime.h>
#include <hip/hip_bf16.h>

#define NEG_SLOPE 0.2f

typedef __attribute__((ext_vector_type(8))) short short8;
typedef __attribute__((ext_vector_type(4))) float f32x4;

__device__ __forceinline__ float lrelu(float x) { return x >= 0.f ? x : NEG_SLOPE * x; }

// pack two fp32 -> bf16x2 (RNE), low = a, high = b
__device__ __forceinline__ unsigned pack_bf2(float a, float b) {
    unsigned ua = __float_as_uint(a), ub = __float_as_uint(b);
    ua = (ua + 0x7fffu + ((ua >> 16) & 1u)) >> 16;
    ub = (ub + 0x7fffu + ((ub >> 16) & 1u)) & 0xffff0000u;
    return ua | ub;
}
__device__ __forceinline__ float2 unpack_bf2(unsigned u) {
    return make_float2(__uint_as_float(u << 16), __uint_as_float(u & 0xffff0000u));
}
__device__ __forceinline__ unsigned short bf16_of(float a) {
    unsigned ua = __float_as_uint(a);
    return (unsigned short)((ua + 0x7fffu + ((ua >> 16) & 1u)) >> 16);
}

// ================= CSR build, round-7: two-level counting sort, all counts in LDS =================
// Partition = 128 consecutive node ids (p = d >> 7). NPART = ceil(n/128) ~ 782.
// NBLK chunk blocks stream the edge list; per-(block,partition) counts -> scan -> deterministic
// bases -> bucket scatter (packed int2). Then one block per partition builds row_ptr + csr_src
// entirely in LDS (histogram, exclusive scan, rank cursors). ZERO global atomics.
#define NBLK 256

// Pass 1: per-block partition histogram (LDS atomics only).
__global__ __launch_bounds__(256) void pcount_kernel(const int* __restrict__ dst,
                                                     int* __restrict__ blk_cnt,
                                                     int etot, int npart, int chunk) {
    __shared__ int cnt[800];
    for (int c = threadIdx.x; c < npart; c += 256) cnt[c] = 0;
    __syncthreads();
    int e0 = blockIdx.x * chunk, e1 = min(etot, e0 + chunk);
    for (int e = e0 + (int)threadIdx.x; e < e1; e += 256)
        atomicAdd(&cnt[dst[e] >> 7], 1);
    __syncthreads();
    for (int c = threadIdx.x; c < npart; c += 256)
        blk_cnt[(size_t)blockIdx.x * npart + c] = cnt[c];  // coalesced
}

// Pass 2a: per-partition scan over the NBLK chunk blocks (one block per partition column).
__global__ __launch_bounds__(256) void pscanA_kernel(const int* __restrict__ blk_cnt,
                                                     int* __restrict__ blk_base,
                                                     int* __restrict__ ptot, int npart) {
    __shared__ int sm[256];
    int t = threadIdx.x, c = blockIdx.x;
    int v = blk_cnt[(size_t)t * npart + c];
    sm[t] = v;
    __syncthreads();
    for (int off = 1; off < 256; off <<= 1) {
        int u = (t >= off) ? sm[t - off] : 0;
        __syncthreads();
        sm[t] += u;
        __syncthreads();
    }
    blk_base[(size_t)t * npart + c] = sm[t] - v;  // block-local exclusive
    if (t == 255) ptot[c] = sm[t];
}

// Pass 2b: cross-partition exclusive scan of totals -> colbase[npart+1].
__global__ __launch_bounds__(1024) void pscanB_kernel(const int* __restrict__ ptot,
                                                      int* __restrict__ colbase,
                                                      int npart, int etot) {
    __shared__ int sm[1024];
    int t = threadIdx.x;
    int v = (t < npart) ? ptot[t] : 0;
    sm[t] = v;
    __syncthreads();
    for (int off = 1; off < 1024; off <<= 1) {
        int u = (t >= off) ? sm[t - off] : 0;
        __syncthreads();
        sm[t] += u;
        __syncthreads();
    }
    if (t < npart) colbase[t] = sm[t] - v;
    if (t == 0) colbase[npart] = etot;
}

// Pass 3: bucket scatter into partition-sorted packed (dst,src) list. LDS cursors, no global atomics.
__global__ __launch_bounds__(256) void pscatter_kernel(const int* __restrict__ src,
                                                       const int* __restrict__ dst,
                                                       const int* __restrict__ blk_base,
                                                       const int* __restrict__ colbase,
                                                       int2* __restrict__ eb,
                                                       int etot, int npart, int chunk) {
    __shared__ int cur[800];
    for (int c = threadIdx.x; c < npart; c += 256)
        cur[c] = colbase[c] + blk_base[(size_t)blockIdx.x * npart + c];
    __syncthreads();
    int e0 = blockIdx.x * chunk, e1 = min(etot, e0 + chunk);
    for (int e = e0 + (int)threadIdx.x; e < e1; e += 256) {
        int d = dst[e], s = src[e];
        int pos = atomicAdd(&cur[d >> 7], 1);
        eb[pos] = make_int2(d, s);
    }
}

// Pass 4: per-partition CSR finalize — LDS histogram + scan + rank cursors.
// row_ptr[d] = colbase[p] + excl[d-lo]; csr_src written into contiguous partition region.
__global__ __launch_bounds__(256) void build_kernel(const int2* __restrict__ eb,
                                                    const int* __restrict__ colbase,
                                                    int* __restrict__ row_ptr,
                                                    int* __restrict__ csr_src,
                                                    int n, int etot) {
    __shared__ int cnt[128];
    __shared__ int sm[128];
    __shared__ int cur[128];
    int p = blockIdx.x, t = threadIdx.x;
    int lo = p << 7;
    int e0 = colbase[p], e1 = colbase[p + 1];
    if (t < 128) cnt[t] = 0;
    __syncthreads();
    for (int e = e0 + t; e < e1; e += 256)
        atomicAdd(&cnt[eb[e].x & 127], 1);
    __syncthreads();
    int v = 0;
    if (t < 128) { v = cnt[t]; sm[t] = v; }
    __syncthreads();
    for (int off = 1; off < 128; off <<= 1) {
        int u = (t < 128 && t >= off) ? sm[t - off] : 0;
        __syncthreads();
        if (t < 128) sm[t] += u;
        __syncthreads();
    }
    if (t < 128) {
        int ex = e0 + sm[t] - v;
        cur[t] = ex;
        int node = lo + t;
        if (node < n) row_ptr[node] = ex;
    }
    if (p == 0 && t == 0) row_ptr[n] = etot;
    __syncthreads();
    for (int e = e0 + t; e < e1; e += 256) {
        int2 ds = eb[e];
        int pos = atomicAdd(&cur[ds.x & 127], 1);
        csr_src[pos] = ds.y;
    }
}

// ---------------- W1 pre-convert: fp32 [256][64] -> bf16 transposed [64][256] ----------------
__global__ __launch_bounds__(256) void w1cvt_kernel(const float* __restrict__ W1,
                                                    unsigned short* __restrict__ W1t) {
    int t = blockIdx.x * 256 + threadIdx.x;  // 16384 total
    int k = t >> 6, nn = t & 63;
    W1t[(size_t)nn * 256 + k] = bf16_of(W1[t]);
}

// ---------------- Layer 1 GEMM via MFMA, zero LDS: h1(bf16) = x @ W1 ----------------
__global__ __launch_bounds__(256) void gemm1_kernel(const float* __restrict__ x,
                                                    const unsigned short* __restrict__ W1t,
                                                    unsigned short* __restrict__ h1b, int n) {
    int tid = threadIdx.x;
    int w = tid >> 6, lane = tid & 63;
    int p = lane & 15, quad = lane >> 4;
    int r0 = blockIdx.x * 64;
    int row = r0 + 16 * w + p;
    const float* xrow = x + (size_t)row * 256;
    f32x4 z = {0.f, 0.f, 0.f, 0.f};
    f32x4 acc[4] = {z, z, z, z};
#pragma unroll
    for (int kc = 0; kc < 8; ++kc) {
        int k0 = kc * 32 + quad * 8;
        float4 v0 = make_float4(0.f, 0.f, 0.f, 0.f), v1 = v0;
        if (row < n) {
            v0 = *(const float4*)(xrow + k0);
            v1 = *(const float4*)(xrow + k0 + 4);
        }
        union { uint4 u; short8 s; } a;
        a.u = make_uint4(pack_bf2(v0.x, v0.y), pack_bf2(v0.z, v0.w),
                         pack_bf2(v1.x, v1.y), pack_bf2(v1.z, v1.w));
#pragma unroll
        for (int t = 0; t < 4; ++t) {
            short8 b = *(const short8*)(W1t + (size_t)(16 * t + p) * 256 + k0);
            acc[t] = __builtin_amdgcn_mfma_f32_16x16x32_bf16(a.s, b, acc[t], 0, 0, 0);
        }
    }
#pragma unroll
    for (int t = 0; t < 4; ++t)
#pragma unroll
        for (int r = 0; r < 4; ++r) {
            int gr = r0 + 16 * w + quad * 4 + r;
            if (gr < n) h1b[(size_t)gr * 64 + 16 * t + p] = bf16_of(acc[t][r]);
        }
}

// alpha1 from bf16 h1: 8 rows/block (2 rows per wave, 32 lanes each)
__global__ __launch_bounds__(256) void alpha1_kernel(const unsigned short* __restrict__ h1b,
                                                     const float* __restrict__ att_s,
                                                     const float* __restrict__ att_d,
                                                     float* __restrict__ as1,
                                                     float* __restrict__ ad1, int n) {
    int wid = threadIdx.x >> 6, lane = threadIdx.x & 63;
    int p = lane & 31;
    int r = blockIdx.x * 8 + wid * 2 + (lane >> 5);
    if (r >= n) return;
    float2 sc = *(const float2*)(att_s + 2 * p);
    float2 dc = *(const float2*)(att_d + 2 * p);
    float2 h = unpack_bf2(((const unsigned*)h1b)[(size_t)r * 32 + p]);
    float ps = h.x * sc.x + h.y * sc.y;
    float pd = h.x * dc.x + h.y * dc.y;
    ps += __shfl_xor(ps, 1); pd += __shfl_xor(pd, 1);
    ps += __shfl_xor(ps, 2); pd += __shfl_xor(pd, 2);
    if ((p & 3) == 0) {
        as1[(size_t)r * 8 + (p >> 2)] = ps;
        ad1[(size_t)r * 8 + (p >> 2)] = pd;
    }
}

// ---------------- Layer 1 aggregation: SINGLE-PASS (shift-free softmax) ----------------
// v = lrelu(alpha_src+alpha_dst) is bounded (|v| <~ 2), so exp(v) cannot overflow:
// out = (sum_e exp(v_e) h[src_e]) / (sum_e exp(v_e)) needs no max subtraction.
__global__ __launch_bounds__(256) void agg1_kernel(const unsigned short* __restrict__ h1b,
                                                   const float* __restrict__ as1,
                                                   const float* __restrict__ ad1,
                                                   const float* __restrict__ b1,
                                                   const int* __restrict__ row_ptr,
                                                   const int* __restrict__ csr_src,
                                                   float* __restrict__ elu1, int n) {
    int lane = threadIdx.x & 63;
    int node = blockIdx.x * 4 + (threadIdx.x >> 6);
    if (node >= n) return;
    int start = row_ptr[node], end = row_ptr[node + 1];
    int slot = lane >> 3, hd = lane & 7;
    float adh = ad1[(size_t)node * 8 + hd];
    int q = lane >> 5, p = lane & 31, hp = p >> 2;
    const unsigned* h1u = (const unsigned*)h1b;  // row stride 32 uints (128B)
    float2 o = make_float2(0.f, 0.f);
    float den = 0.f;
    for (int base = start; base < end; base += 64) {
        int nloc = min(64, end - base);
        int eidx = base + lane;
        int sAll = (eidx < end) ? csr_src[eidx] : 0;  // coalesced
        for (int e0 = 0; e0 < nloc; e0 += 8) {
            // weight for edge e0+slot, head hd (8 edges x 8 heads across the wave)
            int s = __shfl(sAll, e0 + slot);
            float v = lrelu(as1[(size_t)s * 8 + hd] + adh);
            float w = (e0 + slot < nloc) ? __expf(v) : 0.f;
            den += w;
            // weighted gather: lane (q,p) = channel pair 2p..2p+1, edges j+q
#pragma unroll
            for (int j = 0; j < 8; j += 2) {
                int sj = __shfl(s, (j + q) * 8);
                float wj = __shfl(w, (j + q) * 8 + hp);
                float2 hf = unpack_bf2(h1u[(size_t)sj * 32 + p]);
                o.x = fmaf(hf.x, wj, o.x);
                o.y = fmaf(hf.y, wj, o.y);
            }
        }
    }
    // den is per (slot,hd): reduce over slot bits (3,4,5) so den[hd] is wave-wide
    den += __shfl_xor(den, 8);
    den += __shfl_xor(den, 16);
    den += __shfl_xor(den, 32);
    float inv = 1.f / __shfl(den, hp);  // lane hp holds hd==hp
    o.x += __shfl_xor(o.x, 32);
    o.y += __shfl_xor(o.y, 32);
    if (lane < 32) {
        float2 bb = *(const float2*)(b1 + 2 * p);
        float v0 = o.x * inv + bb.x, v1 = o.y * inv + bb.y;
        v0 = v0 > 0.f ? v0 : __expf(v0) - 1.f;
        v1 = v1 > 0.f ? v1 : __expf(v1) - 1.f;
        *(float2*)(elu1 + (size_t)node * 64 + 2 * p) = make_float2(v0, v1);
    }
}

// ---------------- Layer 2 GEMM: h2(bf16) = elu1 @ W2, fused alpha2 ----------------
__global__ __launch_bounds__(256) void gemm2_kernel(const float* __restrict__ elu1,
                                                    const float* __restrict__ W2,
                                                    const float* __restrict__ att_s,
                                                    const float* __restrict__ att_d,
                                                    unsigned short* __restrict__ h2b,
                                                    float* __restrict__ as2,
                                                    float* __restrict__ ad2, int n) {
    __shared__ float As[64][132];
    __shared__ float Bs[64][40];
    int tid = threadIdx.x;
    int r0 = blockIdx.x * 128;
    int cx = tid & 7, ry = tid >> 3;
    float sa[5], da[5];
#pragma unroll
    for (int j = 0; j < 5; ++j) {
        sa[j] = att_s[5 * cx + j];
        da[j] = att_d[5 * cx + j];
    }
    for (int t = tid; t < 640; t += 256) {
        int k = t / 10, cq = t % 10;
        *(float4*)&Bs[k][4 * cq] = *(const float4*)(W2 + (size_t)k * 40 + 4 * cq);
    }
    for (int t = tid; t < 2048; t += 256) {
        int row = t >> 4, kq = t & 15;
        int gr = r0 + row;
        float4 av = make_float4(0.f, 0.f, 0.f, 0.f);
        if (gr < n) av = *(const float4*)(elu1 + (size_t)gr * 64 + 4 * kq);
        As[4 * kq + 0][row] = av.x;
        As[4 * kq + 1][row] = av.y;
        As[4 * kq + 2][row] = av.z;
        As[4 * kq + 3][row] = av.w;
    }
    __syncthreads();
    float acc[4][5] = {{0.f}};
#pragma unroll 8
    for (int k = 0; k < 64; ++k) {
        float4 a = *(const float4*)&As[k][4 * ry];
        float ar[4] = {a.x, a.y, a.z, a.w};
        float br[5];
#pragma unroll
        for (int j = 0; j < 5; ++j) br[j] = Bs[k][5 * cx + j];
#pragma unroll
        for (int i = 0; i < 4; ++i)
#pragma unroll
            for (int j = 0; j < 5; ++j) acc[i][j] = fmaf(ar[i], br[j], acc[i][j]);
    }
#pragma unroll
    for (int i = 0; i < 4; ++i) {
        int gr = r0 + 4 * ry + i;
        float ps = 0.f, pd = 0.f;
#pragma unroll
        for (int j = 0; j < 5; ++j) {
            ps = fmaf(acc[i][j], sa[j], ps);
            pd = fmaf(acc[i][j], da[j], pd);
        }
        ps += __shfl_xor(ps, 1); pd += __shfl_xor(pd, 1);
        ps += __shfl_xor(ps, 2); pd += __shfl_xor(pd, 2);
        ps += __shfl_xor(ps, 4); pd += __shfl_xor(pd, 4);
        if (gr < n) {
#pragma unroll
            for (int j = 0; j < 5; ++j) h2b[(size_t)gr * 40 + 5 * cx + j] = bf16_of(acc[i][j]);
            if (cx == 0) {
                as2[gr] = ps;
                ad2[gr] = pd;
            }
        }
    }
}

// ---------------- Layer 2 aggregation (single-pass) + bias + log_softmax ----------------
__global__ __launch_bounds__(256) void agg2_kernel(const unsigned short* __restrict__ h2b,
                                                   const float* __restrict__ as2,
                                                   const float* __restrict__ ad2,
                                                   const float* __restrict__ b2,
                                                   const int* __restrict__ row_ptr,
                                                   const int* __restrict__ csr_src,
                                                   float* __restrict__ out, int n) {
    int lane = threadIdx.x & 63;
    int node = blockIdx.x * 4 + (threadIdx.x >> 6);
    if (node >= n) return;
    int start = row_ptr[node], end = row_ptr[node + 1];
    float adn = ad2[node];

    int q = lane >> 5, p = lane & 31;
    int pc = min(p, 19);
    const unsigned* h2u = (const unsigned*)h2b;  // row stride 20 uints (80B)
    float2 o = make_float2(0.f, 0.f);
    float den = 0.f;
    for (int base = start; base < end; base += 64) {
        int nloc = min(64, end - base);
        int eidx = base + lane;
        bool valid = eidx < end;
        int sAll = valid ? csr_src[eidx] : 0;
        float v = lrelu(as2[sAll] + adn);
        float w = valid ? __expf(v) : 0.f;
        den += w;
        for (int g = 0; g < nloc; g += 8) {
#pragma unroll
            for (int j = 0; j < 8; j += 2) {
                int idx = g + j + q;
                int sj = __shfl(sAll, idx);
                float wj = __shfl(w, idx);
                float2 hf = unpack_bf2(h2u[(size_t)sj * 20 + pc]);
                o.x = fmaf(hf.x, wj, o.x);
                o.y = fmaf(hf.y, wj, o.y);
            }
        }
    }
#pragma unroll
    for (int off = 1; off < 64; off <<= 1) den += __shfl_xor(den, off);
    float inv = 1.f / den;
    o.x += __shfl_xor(o.x, 32);
    o.y += __shfl_xor(o.y, 32);
    bool act = (lane < 32) && (p < 20);
    float v0 = -1e30f, v1 = -1e30f;
    if (act) {
        float2 bb = *(const float2*)(b2 + 2 * p);
        v0 = o.x * inv + bb.x;
        v1 = o.y * inv + bb.y;
    }
    float vm = fmaxf(v0, v1);
#pragma unroll
    for (int off = 1; off < 64; off <<= 1) vm = fmaxf(vm, __shfl_xor(vm, off));
    float ex = act ? (__expf(v0 - vm) + __expf(v1 - vm)) : 0.f;
#pragma unroll
    for (int off = 1; off < 64; off <<= 1) ex += __shfl_xor(ex, off);
    if (act) {
        float lg = __logf(ex);
        *(float2*)(out + (size_t)node * 40 + 2 * p) = make_float2(v0 - vm - lg, v1 - vm - lg);
    }
}

// ---------------- launch ----------------
extern "C" void kernel_launch(void* const* d_in, const int* in_sizes, int n_in,
                              void* d_out, int out_size, void* d_ws, size_t ws_size,
                              hipStream_t stream) {
    const float* x        = (const float*)d_in[0];
    const float* W1       = (const float*)d_in[1];
    const float* att_src1 = (const float*)d_in[2];
    const float* att_dst1 = (const float*)d_in[3];
    const float* b1       = (const float*)d_in[4];
    const float* W2       = (const float*)d_in[5];
    const float* att_src2 = (const float*)d_in[6];
    const float* att_dst2 = (const float*)d_in[7];
    const float* b2       = (const float*)d_in[8];
    const int*   ei       = (const int*)d_in[9];

    int n    = in_sizes[0] / 256;   // 100000
    int etot = in_sizes[9] / 2;     // 1700000
    const int* srcp = ei;
    const int* dstp = ei + etot;

    int npart = (n + 127) >> 7;           // 782
    int chunk = (etot + NBLK - 1) / NBLK; // ~6641

    char* ws = (char*)d_ws;
    size_t off = 0;
    unsigned short* h1b = (unsigned short*)(ws + off); off += (size_t)n * 64 * 2;
    unsigned short* h2b = (unsigned short*)(ws + off); off += (size_t)n * 40 * 2;
    unsigned short* W1t = (unsigned short*)(ws + off); off += (size_t)64 * 256 * 2;
    float* elu1 = (float*)(ws + off); off += (size_t)n * 64 * 4;
    float* as1  = (float*)(ws + off); off += (size_t)n * 8 * 4;
    float* ad1  = (float*)(ws + off); off += (size_t)n * 8 * 4;
    float* as2  = (float*)(ws + off); off += (size_t)n * 4;
    float* ad2  = (float*)(ws + off); off += (size_t)n * 4;
    int* row_ptr = (int*)(ws + off); off += (size_t)(n + 64) * 4;
    int* csr_src = (int*)(ws + off); off += (size_t)etot * 4;
    int* blk_cnt = (int*)(ws + off); off += (size_t)NBLK * npart * 4;
    int* blk_base= (int*)(ws + off); off += (size_t)NBLK * npart * 4;
    int* ptot    = (int*)(ws + off); off += (size_t)npart * 4;
    int* colbase = (int*)(ws + off); off += (size_t)(npart + 1) * 4;
    float* outp = (float*)d_out;

    // packed bucket list aliases elu1 (etot*8 = 13.6MB <= n*64*4 = 25.6MB);
    // elu1 is only written by agg1, after build_kernel completes (stream-ordered).
    int2* eb = (int2*)elu1;

    pcount_kernel<<<NBLK, 256, 0, stream>>>(dstp, blk_cnt, etot, npart, chunk);
    pscanA_kernel<<<npart, 256, 0, stream>>>(blk_cnt, blk_base, ptot, npart);
    pscanB_kernel<<<1, 1024, 0, stream>>>(ptot, colbase, npart, etot);
    pscatter_kernel<<<NBLK, 256, 0, stream>>>(srcp, dstp, blk_base, colbase, eb, etot, npart, chunk);
    build_kernel<<<npart, 256, 0, stream>>>(eb, colbase, row_ptr, csr_src, n, etot);

    int nb4 = (n + 3) / 4;
    w1cvt_kernel<<<64, 256, 0, stream>>>(W1, W1t);
    gemm1_kernel<<<(n + 63) / 64, 256, 0, stream>>>(x, W1t, h1b, n);
    alpha1_kernel<<<(n + 7) / 8, 256, 0, stream>>>(h1b, att_src1, att_dst1, as1, ad1, n);
    agg1_kernel<<<nb4, 256, 0, stream>>>(h1b, as1, ad1, b1, row_ptr, csr_src, elu1, n);
    gemm2_kernel<<<(n + 127) / 128, 256, 0, stream>>>(elu1, W2, att_src2, att_dst2, h2b, as2, ad2, n);
    agg2_kernel<<<nb4, 256, 0, stream>>>(h2b, as2, ad2, b2, row_ptr, csr_src, outp, n);
}

// Round 4
// 386.366 us; speedup vs baseline: 1.2751x; 1.0045x over previous
//
#include <hip/hip_runtime.h>
#include <hip/hip_bf16.h>

#define NEG_SLOPE 0.2f

typedef __attribute__((ext_vector_type(8))) short short8;
typedef __attribute__((ext_vector_type(4))) float f32x4;
typedef __attribute__((ext_vector_type(2))) float f32x2;

__device__ __forceinline__ float lrelu(float x) { return x >= 0.f ? x : NEG_SLOPE * x; }

// pack two fp32 -> bf16x2 (RNE), low = a, high = b
__device__ __forceinline__ unsigned pack_bf2(float a, float b) {
    unsigned ua = __float_as_uint(a), ub = __float_as_uint(b);
    ua = (ua + 0x7fffu + ((ua >> 16) & 1u)) >> 16;
    ub = (ub + 0x7fffu + ((ub >> 16) & 1u)) & 0xffff0000u;
    return ua | ub;
}
__device__ __forceinline__ float2 unpack_bf2(unsigned u) {
    return make_float2(__uint_as_float(u << 16), __uint_as_float(u & 0xffff0000u));
}
__device__ __forceinline__ f32x2 unpack_bf2v(unsigned u) {
    f32x2 r;
    r.x = __uint_as_float(u << 16);
    r.y = __uint_as_float(u & 0xffff0000u);
    return r;
}
__device__ __forceinline__ unsigned short bf16_of(float a) {
    unsigned ua = __float_as_uint(a);
    return (unsigned short)((ua + 0x7fffu + ((ua >> 16) & 1u)) >> 16);
}
// packed fp32 fma: c += a*b on both halves (1 VOP3P instr, CDNA dual-fp32)
__device__ __forceinline__ f32x2 pk_fma(f32x2 a, f32x2 b, f32x2 c) {
    asm("v_pk_fma_f32 %0, %1, %2, %0" : "+v"(c) : "v"(a), "v"(b));
    return c;
}

// ================= CSR build: two-level counting sort, all counts in LDS =================
#define NBLK 256

// gemm1 body: 64 rows/block, MFMA, zero-LDS
__device__ __forceinline__ void gemm1_body(int bid, const float* __restrict__ x,
                                           const unsigned short* __restrict__ W1t,
                                           unsigned short* __restrict__ h1b, int n) {
    int tid = threadIdx.x;
    int w = tid >> 6, lane = tid & 63;
    int p = lane & 15, quad = lane >> 4;
    int r0 = bid * 64;
    int row = r0 + 16 * w + p;
    const float* xrow = x + (size_t)row * 256;
    f32x4 z = {0.f, 0.f, 0.f, 0.f};
    f32x4 acc[4] = {z, z, z, z};
#pragma unroll
    for (int kc = 0; kc < 8; ++kc) {
        int k0 = kc * 32 + quad * 8;
        float4 v0 = make_float4(0.f, 0.f, 0.f, 0.f), v1 = v0;
        if (row < n) {
            v0 = *(const float4*)(xrow + k0);
            v1 = *(const float4*)(xrow + k0 + 4);
        }
        union { uint4 u; short8 s; } a;
        a.u = make_uint4(pack_bf2(v0.x, v0.y), pack_bf2(v0.z, v0.w),
                         pack_bf2(v1.x, v1.y), pack_bf2(v1.z, v1.w));
#pragma unroll
        for (int t = 0; t < 4; ++t) {
            short8 b = *(const short8*)(W1t + (size_t)(16 * t + p) * 256 + k0);
            acc[t] = __builtin_amdgcn_mfma_f32_16x16x32_bf16(a.s, b, acc[t], 0, 0, 0);
        }
    }
#pragma unroll
    for (int t = 0; t < 4; ++t)
#pragma unroll
        for (int r = 0; r < 4; ++r) {
            int gr = r0 + 16 * w + quad * 4 + r;
            if (gr < n) h1b[(size_t)gr * 64 + 16 * t + p] = bf16_of(acc[t][r]);
        }
}

// Fused: gemm1 (blocks [0,g1)) ∥ pcount (blocks [g1, g1+NBLK)) — independent work, overlapped pipes.
__global__ __launch_bounds__(256) void fusedA_kernel(const float* __restrict__ x,
                                                     const unsigned short* __restrict__ W1t,
                                                     unsigned short* __restrict__ h1b, int n,
                                                     const int* __restrict__ dst,
                                                     int* __restrict__ blk_cnt,
                                                     int etot, int npart, int chunk, int g1) {
    if ((int)blockIdx.x < g1) {
        gemm1_body(blockIdx.x, x, W1t, h1b, n);
    } else {
        __shared__ int cnt[800];
        int bid = blockIdx.x - g1;
        for (int c = threadIdx.x; c < npart; c += 256) cnt[c] = 0;
        __syncthreads();
        int e0 = bid * chunk, e1 = min(etot, e0 + chunk);
        for (int e = e0 + (int)threadIdx.x; e < e1; e += 256)
            atomicAdd(&cnt[dst[e] >> 7], 1);
        __syncthreads();
        for (int c = threadIdx.x; c < npart; c += 256)
            blk_cnt[(size_t)bid * npart + c] = cnt[c];
    }
}

// alpha1 body
__device__ __forceinline__ void alpha1_body(int bid, const unsigned short* __restrict__ h1b,
                                            const float* __restrict__ att_s,
                                            const float* __restrict__ att_d,
                                            float* __restrict__ as1,
                                            float* __restrict__ ad1, int n) {
    int wid = threadIdx.x >> 6, lane = threadIdx.x & 63;
    int p = lane & 31;
    int r = bid * 8 + wid * 2 + (lane >> 5);
    if (r >= n) return;
    float2 sc = *(const float2*)(att_s + 2 * p);
    float2 dc = *(const float2*)(att_d + 2 * p);
    float2 h = unpack_bf2(((const unsigned*)h1b)[(size_t)r * 32 + p]);
    float ps = h.x * sc.x + h.y * sc.y;
    float pd = h.x * dc.x + h.y * dc.y;
    ps += __shfl_xor(ps, 1); pd += __shfl_xor(pd, 1);
    ps += __shfl_xor(ps, 2); pd += __shfl_xor(pd, 2);
    if ((p & 3) == 0) {
        as1[(size_t)r * 8 + (p >> 2)] = ps;
        ad1[(size_t)r * 8 + (p >> 2)] = pd;
    }
}

// Fused: alpha1 (blocks [0,ga)) ∥ pscanA (blocks [ga, ga+npart))
__global__ __launch_bounds__(256) void fusedB_kernel(const unsigned short* __restrict__ h1b,
                                                     const float* __restrict__ att_s,
                                                     const float* __restrict__ att_d,
                                                     float* __restrict__ as1,
                                                     float* __restrict__ ad1, int n,
                                                     const int* __restrict__ blk_cnt,
                                                     int* __restrict__ blk_base,
                                                     int* __restrict__ ptot, int npart, int ga) {
    if ((int)blockIdx.x < ga) {
        alpha1_body(blockIdx.x, h1b, att_s, att_d, as1, ad1, n);
    } else {
        __shared__ int sm[256];
        int t = threadIdx.x, c = blockIdx.x - ga;
        int v = blk_cnt[(size_t)t * npart + c];
        sm[t] = v;
        __syncthreads();
        for (int off = 1; off < 256; off <<= 1) {
            int u = (t >= off) ? sm[t - off] : 0;
            __syncthreads();
            sm[t] += u;
            __syncthreads();
        }
        blk_base[(size_t)t * npart + c] = sm[t] - v;  // block-local exclusive
        if (t == 255) ptot[c] = sm[t];
    }
}

// cross-partition exclusive scan of totals -> colbase[npart+1]
__global__ __launch_bounds__(1024) void pscanB_kernel(const int* __restrict__ ptot,
                                                      int* __restrict__ colbase,
                                                      int npart, int etot) {
    __shared__ int sm[1024];
    int t = threadIdx.x;
    int v = (t < npart) ? ptot[t] : 0;
    sm[t] = v;
    __syncthreads();
    for (int off = 1; off < 1024; off <<= 1) {
        int u = (t >= off) ? sm[t - off] : 0;
        __syncthreads();
        sm[t] += u;
        __syncthreads();
    }
    if (t < npart) colbase[t] = sm[t] - v;
    if (t == 0) colbase[npart] = etot;
}

// bucket scatter into partition-sorted packed (d&127 | src<<7) list. LDS cursors, no global atomics.
__global__ __launch_bounds__(256) void pscatter_kernel(const int* __restrict__ src,
                                                       const int* __restrict__ dst,
                                                       const int* __restrict__ blk_base,
                                                       const int* __restrict__ colbase,
                                                       int* __restrict__ eb,
                                                       int etot, int npart, int chunk) {
    __shared__ int cur[800];
    for (int c = threadIdx.x; c < npart; c += 256)
        cur[c] = colbase[c] + blk_base[(size_t)blockIdx.x * npart + c];
    __syncthreads();
    int e0 = blockIdx.x * chunk, e1 = min(etot, e0 + chunk);
    for (int e = e0 + (int)threadIdx.x; e < e1; e += 256) {
        int d = dst[e], s = src[e];
        int pos = atomicAdd(&cur[d >> 7], 1);
        eb[pos] = (d & 127) | (s << 7);
    }
}

// per-partition CSR finalize — LDS histogram + scan + rank cursors
__global__ __launch_bounds__(256) void build_kernel(const int* __restrict__ eb,
                                                    const int* __restrict__ colbase,
                                                    int* __restrict__ row_ptr,
                                                    int* __restrict__ csr_src,
                                                    int n, int etot) {
    __shared__ int cnt[128];
    __shared__ int sm[128];
    __shared__ int cur[128];
    int p = blockIdx.x, t = threadIdx.x;
    int lo = p << 7;
    int e0 = colbase[p], e1 = colbase[p + 1];
    if (t < 128) cnt[t] = 0;
    __syncthreads();
    for (int e = e0 + t; e < e1; e += 256)
        atomicAdd(&cnt[eb[e] & 127], 1);
    __syncthreads();
    int v = 0;
    if (t < 128) { v = cnt[t]; sm[t] = v; }
    __syncthreads();
    for (int off = 1; off < 128; off <<= 1) {
        int u = (t < 128 && t >= off) ? sm[t - off] : 0;
        __syncthreads();
        if (t < 128) sm[t] += u;
        __syncthreads();
    }
    if (t < 128) {
        int ex = e0 + sm[t] - v;
        cur[t] = ex;
        int node = lo + t;
        if (node < n) row_ptr[node] = ex;
    }
    if (p == 0 && t == 0) row_ptr[n] = etot;
    __syncthreads();
    for (int e = e0 + t; e < e1; e += 256) {
        int u = eb[e];
        int pos = atomicAdd(&cur[u & 127], 1);
        csr_src[pos] = u >> 7;
    }
}

// ---------------- W1 pre-convert: fp32 [256][64] -> bf16 transposed [64][256] ----------------
__global__ __launch_bounds__(256) void w1cvt_kernel(const float* __restrict__ W1,
                                                    unsigned short* __restrict__ W1t) {
    int t = blockIdx.x * 256 + threadIdx.x;  // 16384 total
    int k = t >> 6, nn = t & 63;
    W1t[(size_t)nn * 256 + k] = bf16_of(W1[t]);
}

// ---------------- Layer 1 aggregation: single-pass shift-free softmax ----------------
__global__ __launch_bounds__(256) void agg1_kernel(const unsigned short* __restrict__ h1b,
                                                   const float* __restrict__ as1,
                                                   const float* __restrict__ ad1,
                                                   const float* __restrict__ b1,
                                                   const int* __restrict__ row_ptr,
                                                   const int* __restrict__ csr_src,
                                                   float* __restrict__ elu1, int n) {
    int lane = threadIdx.x & 63;
    int node = blockIdx.x * 4 + (threadIdx.x >> 6);
    if (node >= n) return;
    int start = row_ptr[node], end = row_ptr[node + 1];
    int slot = lane >> 3, hd = lane & 7;
    float adh = ad1[(size_t)node * 8 + hd];
    int q = lane >> 5, p = lane & 31, hp = p >> 2;
    const unsigned* h1u = (const unsigned*)h1b;  // row stride 32 uints (128B)
    f32x2 o = {0.f, 0.f};
    float den = 0.f;
    for (int base = start; base < end; base += 64) {
        int nloc = min(64, end - base);
        int eidx = base + lane;
        int sAll = (eidx < end) ? csr_src[eidx] : 0;  // coalesced
        int e0 = 0;
        for (; e0 + 8 <= nloc; e0 += 8) {  // full 8-edge groups, unrolled
            int s = __shfl(sAll, e0 + slot);
            float v = lrelu(as1[(size_t)s * 8 + hd] + adh);
            float w = __expf(v);
            den += w;
#pragma unroll
            for (int j = 0; j < 8; j += 2) {
                int sj = __shfl(s, (j + q) * 8);
                float wj = __shfl(w, (j + q) * 8 + hp);
                f32x2 w2 = {wj, wj};
                o = pk_fma(unpack_bf2v(h1u[(size_t)sj * 32 + p]), w2, o);
            }
        }
        if (e0 < nloc) {  // tail group: dynamic bound
            int s = __shfl(sAll, e0 + slot);
            float v = lrelu(as1[(size_t)s * 8 + hd] + adh);
            float w = (e0 + slot < nloc) ? __expf(v) : 0.f;
            den += w;
            int jmax = nloc - e0;
            for (int j = 0; j < jmax; j += 2) {
                int sj = __shfl(s, (j + q) * 8);
                float wj = __shfl(w, (j + q) * 8 + hp);
                f32x2 w2 = {wj, wj};
                o = pk_fma(unpack_bf2v(h1u[(size_t)sj * 32 + p]), w2, o);
            }
        }
    }
    // den is per (slot,hd): reduce over slot bits (3,4,5)
    den += __shfl_xor(den, 8);
    den += __shfl_xor(den, 16);
    den += __shfl_xor(den, 32);
    float inv = 1.f / __shfl(den, hp);  // lane hp holds hd==hp
    o.x += __shfl_xor(o.x, 32);
    o.y += __shfl_xor(o.y, 32);
    if (lane < 32) {
        float2 bb = *(const float2*)(b1 + 2 * p);
        float v0 = o.x * inv + bb.x, v1 = o.y * inv + bb.y;
        v0 = v0 > 0.f ? v0 : __expf(v0) - 1.f;
        v1 = v1 > 0.f ? v1 : __expf(v1) - 1.f;
        *(float2*)(elu1 + (size_t)node * 64 + 2 * p) = make_float2(v0, v1);
    }
}

// ---------------- Layer 2 GEMM: h2(bf16) = elu1 @ W2, fused alpha2 ----------------
__global__ __launch_bounds__(256) void gemm2_kernel(const float* __restrict__ elu1,
                                                    const float* __restrict__ W2,
                                                    const float* __restrict__ att_s,
                                                    const float* __restrict__ att_d,
                                                    unsigned short* __restrict__ h2b,
                                                    float* __restrict__ as2,
                                                    float* __restrict__ ad2, int n) {
    __shared__ float As[64][132];
    __shared__ float Bs[64][40];
    int tid = threadIdx.x;
    int r0 = blockIdx.x * 128;
    int cx = tid & 7, ry = tid >> 3;
    float sa[5], da[5];
#pragma unroll
    for (int j = 0; j < 5; ++j) {
        sa[j] = att_s[5 * cx + j];
        da[j] = att_d[5 * cx + j];
    }
    for (int t = tid; t < 640; t += 256) {
        int k = t / 10, cq = t % 10;
        *(float4*)&Bs[k][4 * cq] = *(const float4*)(W2 + (size_t)k * 40 + 4 * cq);
    }
    for (int t = tid; t < 2048; t += 256) {
        int row = t >> 4, kq = t & 15;
        int gr = r0 + row;
        float4 av = make_float4(0.f, 0.f, 0.f, 0.f);
        if (gr < n) av = *(const float4*)(elu1 + (size_t)gr * 64 + 4 * kq);
        As[4 * kq + 0][row] = av.x;
        As[4 * kq + 1][row] = av.y;
        As[4 * kq + 2][row] = av.z;
        As[4 * kq + 3][row] = av.w;
    }
    __syncthreads();
    float acc[4][5] = {{0.f}};
#pragma unroll 8
    for (int k = 0; k < 64; ++k) {
        float4 a = *(const float4*)&As[k][4 * ry];
        float ar[4] = {a.x, a.y, a.z, a.w};
        float br[5];
#pragma unroll
        for (int j = 0; j < 5; ++j) br[j] = Bs[k][5 * cx + j];
#pragma unroll
        for (int i = 0; i < 4; ++i)
#pragma unroll
            for (int j = 0; j < 5; ++j) acc[i][j] = fmaf(ar[i], br[j], acc[i][j]);
    }
#pragma unroll
    for (int i = 0; i < 4; ++i) {
        int gr = r0 + 4 * ry + i;
        float ps = 0.f, pd = 0.f;
#pragma unroll
        for (int j = 0; j < 5; ++j) {
            ps = fmaf(acc[i][j], sa[j], ps);
            pd = fmaf(acc[i][j], da[j], pd);
        }
        ps += __shfl_xor(ps, 1); pd += __shfl_xor(pd, 1);
        ps += __shfl_xor(ps, 2); pd += __shfl_xor(pd, 2);
        ps += __shfl_xor(ps, 4); pd += __shfl_xor(pd, 4);
        if (gr < n) {
#pragma unroll
            for (int j = 0; j < 5; ++j) h2b[(size_t)gr * 40 + 5 * cx + j] = bf16_of(acc[i][j]);
            if (cx == 0) {
                as2[gr] = ps;
                ad2[gr] = pd;
            }
        }
    }
}

// ---------------- Layer 2 aggregation (single-pass) + bias + log_softmax ----------------
__global__ __launch_bounds__(256) void agg2_kernel(const unsigned short* __restrict__ h2b,
                                                   const float* __restrict__ as2,
                                                   const float* __restrict__ ad2,
                                                   const float* __restrict__ b2,
                                                   const int* __restrict__ row_ptr,
                                                   const int* __restrict__ csr_src,
                                                   float* __restrict__ out, int n) {
    int lane = threadIdx.x & 63;
    int node = blockIdx.x * 4 + (threadIdx.x >> 6);
    if (node >= n) return;
    int start = row_ptr[node], end = row_ptr[node + 1];
    float adn = ad2[node];

    int q = lane >> 5, p = lane & 31;
    int pc = min(p, 19);
    const unsigned* h2u = (const unsigned*)h2b;  // row stride 20 uints (80B)
    f32x2 o = {0.f, 0.f};
    float den = 0.f;
    for (int base = start; base < end; base += 64) {
        int nloc = min(64, end - base);
        int eidx = base + lane;
        bool valid = eidx < end;
        int sAll = valid ? csr_src[eidx] : 0;
        float v = lrelu(as2[sAll] + adn);
        float w = valid ? __expf(v) : 0.f;
        den += w;
        int g = 0;
        for (; g + 8 <= nloc; g += 8) {
#pragma unroll
            for (int j = 0; j < 8; j += 2) {
                int idx = g + j + q;
                int sj = __shfl(sAll, idx);
                float wj = __shfl(w, idx);
                f32x2 w2 = {wj, wj};
                o = pk_fma(unpack_bf2v(h2u[(size_t)sj * 20 + pc]), w2, o);
            }
        }
        if (g < nloc) {
            int jmax = nloc - g;
            for (int j = 0; j < jmax; j += 2) {
                int idx = g + j + q;
                int sj = __shfl(sAll, idx);
                float wj = __shfl(w, idx);
                f32x2 w2 = {wj, wj};
                o = pk_fma(unpack_bf2v(h2u[(size_t)sj * 20 + pc]), w2, o);
            }
        }
    }
#pragma unroll
    for (int off = 1; off < 64; off <<= 1) den += __shfl_xor(den, off);
    float inv = 1.f / den;
    o.x += __shfl_xor(o.x, 32);
    o.y += __shfl_xor(o.y, 32);
    bool act = (lane < 32) && (p < 20);
    float v0 = -1e30f, v1 = -1e30f;
    if (act) {
        float2 bb = *(const float2*)(b2 + 2 * p);
        v0 = o.x * inv + bb.x;
        v1 = o.y * inv + bb.y;
    }
    float vm = fmaxf(v0, v1);
#pragma unroll
    for (int off = 1; off < 64; off <<= 1) vm = fmaxf(vm, __shfl_xor(vm, off));
    float ex = act ? (__expf(v0 - vm) + __expf(v1 - vm)) : 0.f;
#pragma unroll
    for (int off = 1; off < 64; off <<= 1) ex += __shfl_xor(ex, off);
    if (act) {
        float lg = __logf(ex);
        *(float2*)(out + (size_t)node * 40 + 2 * p) = make_float2(v0 - vm - lg, v1 - vm - lg);
    }
}

// ---------------- launch ----------------
extern "C" void kernel_launch(void* const* d_in, const int* in_sizes, int n_in,
                              void* d_out, int out_size, void* d_ws, size_t ws_size,
                              hipStream_t stream) {
    const float* x        = (const float*)d_in[0];
    const float* W1       = (const float*)d_in[1];
    const float* att_src1 = (const float*)d_in[2];
    const float* att_dst1 = (const float*)d_in[3];
    const float* b1       = (const float*)d_in[4];
    const float* W2       = (const float*)d_in[5];
    const float* att_src2 = (const float*)d_in[6];
    const float* att_dst2 = (const float*)d_in[7];
    const float* b2       = (const float*)d_in[8];
    const int*   ei       = (const int*)d_in[9];

    int n    = in_sizes[0] / 256;   // 100000
    int etot = in_sizes[9] / 2;     // 1700000
    const int* srcp = ei;
    const int* dstp = ei + etot;

    int npart = (n + 127) >> 7;           // 782
    int chunk = (etot + NBLK - 1) / NBLK; // ~6641

    char* ws = (char*)d_ws;
    size_t off = 0;
    unsigned short* h1b = (unsigned short*)(ws + off); off += (size_t)n * 64 * 2;
    unsigned short* h2b = (unsigned short*)(ws + off); off += (size_t)n * 40 * 2;
    unsigned short* W1t = (unsigned short*)(ws + off); off += (size_t)64 * 256 * 2;
    float* elu1 = (float*)(ws + off); off += (size_t)n * 64 * 4;
    float* as1  = (float*)(ws + off); off += (size_t)n * 8 * 4;
    float* ad1  = (float*)(ws + off); off += (size_t)n * 8 * 4;
    float* as2  = (float*)(ws + off); off += (size_t)n * 4;
    float* ad2  = (float*)(ws + off); off += (size_t)n * 4;
    int* row_ptr = (int*)(ws + off); off += (size_t)(n + 64) * 4;
    int* csr_src = (int*)(ws + off); off += (size_t)etot * 4;
    int* blk_cnt = (int*)(ws + off); off += (size_t)NBLK * npart * 4;
    int* blk_base= (int*)(ws + off); off += (size_t)NBLK * npart * 4;
    int* ptot    = (int*)(ws + off); off += (size_t)npart * 4;
    int* colbase = (int*)(ws + off); off += (size_t)(npart + 1) * 4;
    float* outp = (float*)d_out;

    // packed bucket list aliases elu1 (etot*4 = 6.8MB <= n*64*4 = 25.6MB);
    // elu1 is only written by agg1, after build_kernel completes (stream-ordered).
    int* eb = (int*)elu1;

    int g1 = (n + 63) / 64;      // 1563 gemm1 blocks
    int ga = (n + 7) / 8;        // 12500 alpha1 blocks
    int nb4 = (n + 3) / 4;

    w1cvt_kernel<<<64, 256, 0, stream>>>(W1, W1t);
    fusedA_kernel<<<g1 + NBLK, 256, 0, stream>>>(x, W1t, h1b, n, dstp, blk_cnt, etot, npart, chunk, g1);
    fusedB_kernel<<<ga + npart, 256, 0, stream>>>(h1b, att_src1, att_dst1, as1, ad1, n,
                                                  blk_cnt, blk_base, ptot, npart, ga);
    pscanB_kernel<<<1, 1024, 0, stream>>>(ptot, colbase, npart, etot);
    pscatter_kernel<<<NBLK, 256, 0, stream>>>(srcp, dstp, blk_base, colbase, eb, etot, npart, chunk);
    build_kernel<<<npart, 256, 0, stream>>>(eb, colbase, row_ptr, csr_src, n, etot);
    agg1_kernel<<<nb4, 256, 0, stream>>>(h1b, as1, ad1, b1, row_ptr, csr_src, elu1, n);
    gemm2_kernel<<<(n + 127) / 128, 256, 0, stream>>>(elu1, W2, att_src2, att_dst2, h2b, as2, ad2, n);
    agg2_kernel<<<nb4, 256, 0, stream>>>(h2b, as2, ad2, b2, row_ptr, csr_src, outp, n);
}